// Round 2
// baseline (1003.815 us; speedup 1.0000x reference)
//
#include <hip/hip_runtime.h>

#define HW 128
#define GNUM 2
#define BATCH 4
// off_ws: G*B*H*W*18 floats
#define OFF_WS_FLOATS (GNUM * BATCH * HW * HW * 18)

typedef short s16x8 __attribute__((ext_vector_type(8)));
typedef float f32x4 __attribute__((ext_vector_type(4)));

__device__ inline unsigned short f2bf(float f) {
    union { float f; unsigned u; } v;
    v.f = f;
    unsigned r = (v.u + 0x7fffu + ((v.u >> 16) & 1u)) >> 16;
    return (unsigned short)r;
}

// ---------------------------------------------------------------------------
// pw_prep: pre-swizzle pw_w into bf16 B-fragment order for mfma 16x16x32.
// Fragment element: lane l holds B[k=(l>>4)*8+i][n=l&15], f = wv*16 + n,
// kin = j*64 + ks*32 + k.  Layout: [((g*9+j)*4+wv)*2+ks][lane][i]  (512 each)
// ---------------------------------------------------------------------------
__global__ __launch_bounds__(256) void pw_prep(const float* __restrict__ pw_w,
                                               unsigned short* __restrict__ pwt) {
    const int j = blockIdx.x, g = blockIdx.y;
    const int t = threadIdx.x;
    const int wv = t >> 6, lane = t & 63;
    const int f = wv * 16 + (lane & 15);
    const int kbase = (lane >> 4) << 3;
#pragma unroll
    for (int ks = 0; ks < 2; ++ks) {
#pragma unroll
        for (int i = 0; i < 8; ++i) {
            int kin = j * 64 + ks * 32 + kbase + i;
            pwt[((((g * 9 + j) * 4 + wv) * 2 + ks) << 9) + lane * 8 + i] =
                f2bf(pw_w[(g * 576 + kin) * 64 + f]);
        }
    }
}

// ---------------------------------------------------------------------------
// offset_kernel: 3x3 SAME conv, Cg=64 -> 18, split into 16-channel quarters.
// grid (64 tiles, B, G*4). Each block computes a 16x16 tile's partial sum
// over its quarter and atomicAdd's into off_ws (pre-zeroed; off_b added by
// the consumer).  LDS: 18x18 halo x (16ch + 1 pad) = 22 KB -> ~7 blocks/CU.
// ---------------------------------------------------------------------------
__global__ __launch_bounds__(256) void offset_kernel(
    const float* __restrict__ x, const float* __restrict__ off_w,
    float* __restrict__ off_ws) {
    __shared__ float tile[324 * 17];
    const int tileIdx = blockIdx.x;
    const int b = blockIdx.y, gz = blockIdx.z;
    const int g = gz >> 2, q = gz & 3;
    const int h0 = (tileIdx >> 3) << 4, w0 = (tileIdx & 7) << 4;
    const int t = threadIdx.x;
    const int px = t & 15, py = t >> 4;

    for (int i = t; i < 324 * 16; i += 256) {
        int sp = i >> 4, c = i & 15;
        int sy = sp / 18, sx = sp - sy * 18;
        int gy = h0 - 1 + sy, gx = w0 - 1 + sx;
        float v = 0.f;
        if ((unsigned)gy < HW && (unsigned)gx < HW)
            v = x[(((b * HW + gy) * HW + gx) << 7) + (g << 6) + (q << 4) + c];
        tile[sp * 17 + c] = v;
    }
    __syncthreads();

    float acc[18];
#pragma unroll
    for (int o = 0; o < 18; ++o) acc[o] = 0.f;
#pragma unroll
    for (int ky = 0; ky < 3; ++ky)
#pragma unroll
        for (int kx = 0; kx < 3; ++kx) {
            const float* wp =
                off_w + (((g * 3 + ky) * 3 + kx) * 64 + q * 16) * 18;
            const float* tp = tile + ((py + ky) * 18 + px + kx) * 17;
            for (int c = 0; c < 16; ++c) {
                float v = tp[c];
#pragma unroll
                for (int o = 0; o < 18; ++o) acc[o] += v * wp[c * 18 + o];
            }
        }
    float* op = off_ws +
                (((g * BATCH + b) * HW * HW + (h0 + py) * HW + (w0 + px)) * 18);
#pragma unroll
    for (int o = 0; o < 18; ++o) atomicAdd(op + o, acc[o]);
}

// ---------------------------------------------------------------------------
// deform_kernel: fused bilinear-sample -> depthwise 3x3 -> pointwise via
// bf16 MFMA.  Block = 256 thr = one 8x8 px tile of one (b,g).
//   samp: 10x10 halo x 64ch fp32, stride 68           (27200 B)
//   dwa : depthwise out bf16 [px][c], stride 72       ( 9216 B)
// Wave wv owns f-block fb=wv*16; acc = 4 m-tiles of 16x16 C-frags.
// ---------------------------------------------------------------------------
__global__ __launch_bounds__(256) void deform_kernel(
    const float* __restrict__ x, const float* __restrict__ off_ws,
    const float* __restrict__ off_b, const float* __restrict__ dw_w,
    const float* __restrict__ pw_w, const float* __restrict__ pw_b,
    const float* __restrict__ dw_b, const unsigned short* __restrict__ pwt,
    float* __restrict__ out) {
    __shared__ float samp[100 * 68];
    __shared__ unsigned short dwa[64 * 72];
    const int tileIdx = blockIdx.x;
    const int b = blockIdx.y, g = blockIdx.z;
    const int h0 = (tileIdx >> 4) << 3, w0 = (tileIdx & 15) << 3;
    const int t = threadIdx.x;
    const int lane = t & 63;
    const int wv = __builtin_amdgcn_readfirstlane(t >> 6);
    const int fb = wv << 4;
    const int p = lane;
    const int ayp = p >> 3, axp = p & 7;
    const float* xg = x + (g << 6);

    // combined bias: bias2[f] = pw_b[f] + sum_kin pw_w[kin][f]*dw_b[kin]
    float bsum = 0.f;
    {
        const int fcol = fb + (lane & 15);
        for (int kin = (lane >> 4); kin < 576; kin += 4)
            bsum += pw_w[(g * 576 + kin) * 64 + fcol] * dw_b[g * 576 + kin];
        bsum += __shfl_xor(bsum, 16);
        bsum += __shfl_xor(bsum, 32);
        bsum += pw_b[g * 64 + fcol];
    }
    f32x4 acc[4];
#pragma unroll
    for (int mt = 0; mt < 4; ++mt) acc[mt] = (f32x4){bsum, bsum, bsum, bsum};

    for (int j = 0; j < 9; ++j) {
        const int jy = j / 3, jx = j - jy * 3;
        const float obx = off_b[g * 18 + 2 * j];
        const float oby = off_b[g * 18 + 2 * j + 1];
        // B-fragments for this tap (global, L2-hot, pre-swizzled)
        s16x8 bfr[2];
#pragma unroll
        for (int ks = 0; ks < 2; ++ks)
            bfr[ks] = *(const s16x8*)&pwt[((((g * 9 + j) * 4 + wv) * 2 + ks)
                                           << 9) + lane * 8];
        __syncthreads();
        // ---- Phase S: bilinear-sample tap j (sp wave-uniform, lane=channel)
        for (int k = 0; k < 25; ++k) {
            int sp = wv + (k << 2);
            int spy = sp / 10, spx = sp - spy * 10;
            int gy = h0 - 1 + spy, gx = w0 - 1 + spx;
            float val = 0.f;
            if ((unsigned)gy < HW && (unsigned)gx < HW) {
                const float2 off2 = *(const float2*)&off_ws
                    [((g * BATCH + b) * HW * HW + gy * HW + gx) * 18 + 2 * j];
                float ox = off2.x + obx, oy = off2.y + oby;
                float xf = fminf(fmaxf((float)(gx + jx - 1) + ox, 0.f), 127.f);
                float yf = fminf(fmaxf((float)(gy + jy - 1) + oy, 0.f), 127.f);
                float x0 = floorf(xf), y0 = floorf(yf);
                float x1 = fminf(x0 + 1.f, 127.f);
                float y1 = fminf(y0 + 1.f, 127.f);
                float wa = (x1 - xf) * (y1 - yf);
                float wb = (x1 - xf) * (yf - y0);
                float wc = (xf - x0) * (y1 - yf);
                float wd = (xf - x0) * (yf - y0);
                int x0i = (int)x0, y0i = (int)y0;
                int x1i = (int)x1, y1i = (int)y1;
                float va = xg[(((b * HW + y0i) * HW + x0i) << 7) + lane];
                float vb = xg[(((b * HW + y1i) * HW + x0i) << 7) + lane];
                float vc = xg[(((b * HW + y0i) * HW + x1i) << 7) + lane];
                float vd = xg[(((b * HW + y1i) * HW + x1i) << 7) + lane];
                val = wa * va + wb * vb + wc * vc + wd * vd;
            }
            samp[sp * 68 + lane] = val;
        }
        __syncthreads();
        // ---- Phase A: depthwise 3x3, channels [fb, fb+16), bf16 out to dwa
#pragma unroll
        for (int cq = 0; cq < 4; ++cq) {
            int c = fb + (cq << 2);
            float4 d = make_float4(0.f, 0.f, 0.f, 0.f);
#pragma unroll
            for (int ky = 0; ky < 3; ++ky)
#pragma unroll
                for (int kx = 0; kx < 3; ++kx) {
                    const float4 v = *(const float4*)&samp
                        [((ayp + ky) * 10 + axp + kx) * 68 + c];
                    const float4 w = *(const float4*)&dw_w
                        [((g * 3 + ky) * 3 + kx) * 576 + (j << 6) + c];
                    d.x += v.x * w.x;
                    d.y += v.y * w.y;
                    d.z += v.z * w.z;
                    d.w += v.w * w.w;
                }
            ushort4 hv;
            hv.x = f2bf(d.x); hv.y = f2bf(d.y);
            hv.z = f2bf(d.z); hv.w = f2bf(d.w);
            *(ushort4*)&dwa[p * 72 + c] = hv;
        }
        __syncthreads();
        // ---- Phase B: pointwise via MFMA (A from dwa, B prefetched)
#pragma unroll
        for (int ks = 0; ks < 2; ++ks)
#pragma unroll
            for (int mt = 0; mt < 4; ++mt) {
                s16x8 af = *(const s16x8*)&dwa[(mt * 16 + (lane & 15)) * 72 +
                                               ks * 32 + ((lane >> 4) << 3)];
                acc[mt] = __builtin_amdgcn_mfma_f32_16x16x32_bf16(
                    af, bfr[ks], acc[mt], 0, 0, 0);
            }
    }
    // ---- epilogue: C-layout col=lane&15, row=(lane>>4)*4+i
    const int col = lane & 15;
    const int rq = (lane >> 4) << 2;
#pragma unroll
    for (int mt = 0; mt < 4; ++mt)
#pragma unroll
        for (int i = 0; i < 4; ++i) {
            int m = mt * 16 + rq + i;
            out[((b * HW + h0 + (m >> 3)) * HW + (w0 + (m & 7))) * 128 +
                (g << 6) + fb + col] = acc[mt][i];
        }
}

extern "C" void kernel_launch(void* const* d_in, const int* in_sizes, int n_in,
                              void* d_out, int out_size, void* d_ws,
                              size_t ws_size, hipStream_t stream) {
    const float* x = (const float*)d_in[0];
    const float* off_w = (const float*)d_in[1];
    const float* off_b = (const float*)d_in[2];
    const float* dw_w = (const float*)d_in[3];
    const float* dw_b = (const float*)d_in[4];
    const float* pw_w = (const float*)d_in[5];
    const float* pw_b = (const float*)d_in[6];

    float* wsf = (float*)d_ws;
    float* off_ws = wsf;                                      // 9.44 MB
    unsigned short* pwt = (unsigned short*)(wsf + OFF_WS_FLOATS);  // 147 KB

    hipMemsetAsync(off_ws, 0, OFF_WS_FLOATS * sizeof(float), stream);
    pw_prep<<<dim3(9, GNUM), dim3(256), 0, stream>>>(pw_w, pwt);
    offset_kernel<<<dim3(64, BATCH, GNUM * 4), dim3(256), 0, stream>>>(
        x, off_w, off_ws);
    deform_kernel<<<dim3(256, BATCH, GNUM), dim3(256), 0, stream>>>(
        x, off_ws, off_b, dw_w, pw_w, pw_b, dw_b, pwt, (float*)d_out);
}

// Round 3
// 507.093 us; speedup vs baseline: 1.9795x; 1.9795x over previous
//
#include <hip/hip_runtime.h>

#define HW 128
#define GNUM 2
#define BATCH 4
#define OFF_WS_FLOATS (GNUM * BATCH * HW * HW * 18)

typedef short s16x8 __attribute__((ext_vector_type(8)));
typedef float f32x4 __attribute__((ext_vector_type(4)));

__device__ inline unsigned short f2bf(float f) {
    union { float f; unsigned u; } v;
    v.f = f;
    unsigned r = (v.u + 0x7fffu + ((v.u >> 16) & 1u)) >> 16;
    return (unsigned short)r;
}
__device__ inline float blo(unsigned u) {
    union { unsigned u; float f; } v; v.u = u << 16; return v.f;
}
__device__ inline float bhi(unsigned u) {
    union { unsigned u; float f; } v; v.u = u & 0xffff0000u; return v.f;
}

// ---------------------------------------------------------------------------
// bias_kernel: bias2[g][f] = pw_b[g,f] + sum_kin pw_w[g,kin,f]*dw_b[g,kin]
// ---------------------------------------------------------------------------
__global__ void bias_kernel(const float* __restrict__ pw_w,
                            const float* __restrict__ pw_b,
                            const float* __restrict__ dw_b,
                            float* __restrict__ bias2) {
    int g = blockIdx.x;
    int f = threadIdx.x;
    float acc = pw_b[g * 64 + f];
    for (int kin = 0; kin < 576; ++kin)
        acc += pw_w[(g * 576 + kin) * 64 + f] * dw_b[g * 576 + kin];
    bias2[g * 64 + f] = acc;
}

// ---------------------------------------------------------------------------
// pw_prep: pre-swizzle pw_w into bf16 B-fragment order for mfma 16x16x32.
// lane l holds B[k=(l>>4)*8+i][n=l&15], f = wv*16+n, kin = j*64+ks*32+k.
// ---------------------------------------------------------------------------
__global__ __launch_bounds__(256) void pw_prep(const float* __restrict__ pw_w,
                                               unsigned short* __restrict__ pwt) {
    const int j = blockIdx.x, g = blockIdx.y;
    const int t = threadIdx.x;
    const int wv = t >> 6, lane = t & 63;
    const int f = wv * 16 + (lane & 15);
    const int kbase = (lane >> 4) << 3;
#pragma unroll
    for (int ks = 0; ks < 2; ++ks)
#pragma unroll
        for (int i = 0; i < 8; ++i) {
            int kin = j * 64 + ks * 32 + kbase + i;
            pwt[((((g * 9 + j) * 4 + wv) * 2 + ks) << 9) + lane * 8 + i] =
                f2bf(pw_w[(g * 576 + kin) * 64 + f]);
        }
}

// ---------------------------------------------------------------------------
// offset_kernel: 3x3 SAME conv, 64 -> 18, NO atomics.
// grid (64 tiles of 16x16, B, G*2). z = g*2 + oh; block owns 9 output ch
// (o = oh*9 .. +8) over ALL 64 input ch (4 staged quarters of 16).
// LDS 324 sp x 17 (stride 17 = conflict-friendly b32 reads), 22 KB.
// ---------------------------------------------------------------------------
__global__ __launch_bounds__(256) void offset_kernel(
    const float* __restrict__ x, const float* __restrict__ off_w,
    const float* __restrict__ off_b, float* __restrict__ off_ws) {
    __shared__ float tile[324 * 17];
    const int tileIdx = blockIdx.x;
    const int b = blockIdx.y, gz = blockIdx.z;
    const int g = gz >> 1, oh = gz & 1;
    const int h0 = (tileIdx >> 3) << 4, w0 = (tileIdx & 7) << 4;
    const int t = threadIdx.x;
    const int px = t & 15, py = t >> 4;

    float acc[9];
#pragma unroll
    for (int o = 0; o < 9; ++o) acc[o] = off_b[g * 18 + oh * 9 + o];

    for (int q = 0; q < 4; ++q) {
        __syncthreads();
        for (int i = t; i < 324 * 16; i += 256) {
            int sp = i >> 4, c = i & 15;
            int sy = sp / 18, sx = sp - sy * 18;
            int gy = h0 - 1 + sy, gx = w0 - 1 + sx;
            float v = 0.f;
            if ((unsigned)gy < HW && (unsigned)gx < HW)
                v = x[(((b * HW + gy) * HW + gx) << 7) + (g << 6) + (q << 4) + c];
            tile[sp * 17 + c] = v;
        }
        __syncthreads();
#pragma unroll
        for (int ky = 0; ky < 3; ++ky)
#pragma unroll
            for (int kx = 0; kx < 3; ++kx) {
                const float* wq = off_w +
                    (((g * 3 + ky) * 3 + kx) * 64 + (q << 4)) * 18 + oh * 9;
                const float* tp = tile + ((py + ky) * 18 + px + kx) * 17;
#pragma unroll 4
                for (int c = 0; c < 16; ++c) {
                    float v = tp[c];
#pragma unroll
                    for (int o = 0; o < 9; ++o) acc[o] += v * wq[c * 18 + o];
                }
            }
    }
    float* op = off_ws +
                (((g * BATCH + b) * HW * HW + (h0 + py) * HW + (w0 + px)) * 18) +
                oh * 9;
#pragma unroll
    for (int o = 0; o < 9; ++o) op[o] = acc[o];
}

// ---------------------------------------------------------------------------
// deform_kernel: fused bilinear-sample -> depthwise 3x3 -> pointwise MFMA.
// Block = 256 thr = one 8x8 px tile of one (b,g).
//   samp: 10x10 halo x 64ch BF16, stride 72  (14400 B)
//   dwa : depthwise out bf16 [px][c], stride 72 (9216 B)   -> 23.6 KB LDS
// 2 barriers per tap.  Wave wv owns f-block fb = wv*16.
// ---------------------------------------------------------------------------
__global__ __launch_bounds__(256) void deform_kernel(
    const float* __restrict__ x, const float* __restrict__ off_ws,
    const float* __restrict__ off_b, const float* __restrict__ dw_w,
    const unsigned short* __restrict__ pwt, const float* __restrict__ bias2,
    float* __restrict__ out) {
    __shared__ unsigned short samp[100 * 72];
    __shared__ unsigned short dwa[64 * 72];
    const int tileIdx = blockIdx.x;
    const int b = blockIdx.y, g = blockIdx.z;
    const int h0 = (tileIdx >> 4) << 3, w0 = (tileIdx & 15) << 3;
    const int t = threadIdx.x;
    const int lane = t & 63;
    const int wv = __builtin_amdgcn_readfirstlane(t >> 6);
    const int fb = wv << 4;
    const int p = lane;
    const int ayp = p >> 3, axp = p & 7;
    const float* xg = x + (g << 6);

    const float bs = bias2[g * 64 + fb + (lane & 15)];
    f32x4 acc[4];
#pragma unroll
    for (int mt = 0; mt < 4; ++mt) acc[mt] = (f32x4){bs, bs, bs, bs};

    for (int j = 0; j < 9; ++j) {
        const int jy = j / 3, jx = j - jy * 3;
        const float obx = off_b[g * 18 + 2 * j];
        const float oby = off_b[g * 18 + 2 * j + 1];
        s16x8 bfr[2];
#pragma unroll
        for (int ks = 0; ks < 2; ++ks)
            bfr[ks] = *(const s16x8*)&pwt[((((g * 9 + j) * 4 + wv) * 2 + ks)
                                           << 9) + lane * 8];
        // ---- Phase S: sample tap j (sp wave-uniform, lane = channel)
        for (int k = 0; k < 25; ++k) {
            int sp = wv + (k << 2);
            int spy = sp / 10, spx = sp - spy * 10;
            int gy = h0 - 1 + spy, gx = w0 - 1 + spx;
            float val = 0.f;
            if ((unsigned)gy < HW && (unsigned)gx < HW) {
                const float2 off2 = *(const float2*)&off_ws
                    [((g * BATCH + b) * HW * HW + gy * HW + gx) * 18 + 2 * j];
                float ox = off2.x + obx, oy = off2.y + oby;
                float xf = fminf(fmaxf((float)(gx + jx - 1) + ox, 0.f), 127.f);
                float yf = fminf(fmaxf((float)(gy + jy - 1) + oy, 0.f), 127.f);
                float x0 = floorf(xf), y0 = floorf(yf);
                float x1 = fminf(x0 + 1.f, 127.f);
                float y1 = fminf(y0 + 1.f, 127.f);
                float wa = (x1 - xf) * (y1 - yf);
                float wb = (x1 - xf) * (yf - y0);
                float wc = (xf - x0) * (y1 - yf);
                float wd = (xf - x0) * (yf - y0);
                int x0i = (int)x0, y0i = (int)y0;
                int x1i = (int)x1, y1i = (int)y1;
                float va = xg[(((b * HW + y0i) * HW + x0i) << 7) + lane];
                float vb = xg[(((b * HW + y1i) * HW + x0i) << 7) + lane];
                float vc = xg[(((b * HW + y0i) * HW + x1i) << 7) + lane];
                float vd = xg[(((b * HW + y1i) * HW + x1i) << 7) + lane];
                val = wa * va + wb * vb + wc * vc + wd * vd;
            }
            samp[sp * 72 + lane] = f2bf(val);
        }
        __syncthreads();
        // ---- Phase A: depthwise 3x3, channels [fb, fb+16), bf16 in/out
#pragma unroll
        for (int cq = 0; cq < 2; ++cq) {
            const int c8 = fb + (cq << 3);
            float d0 = 0.f, d1 = 0.f, d2 = 0.f, d3 = 0.f;
            float d4 = 0.f, d5 = 0.f, d6 = 0.f, d7 = 0.f;
#pragma unroll
            for (int ky = 0; ky < 3; ++ky)
#pragma unroll
                for (int kx = 0; kx < 3; ++kx) {
                    const uint4 hv = *(const uint4*)&samp
                        [((ayp + ky) * 10 + axp + kx) * 72 + c8];
                    const float* wr =
                        &dw_w[((g * 3 + ky) * 3 + kx) * 576 + (j << 6) + c8];
                    d0 += blo(hv.x) * wr[0]; d1 += bhi(hv.x) * wr[1];
                    d2 += blo(hv.y) * wr[2]; d3 += bhi(hv.y) * wr[3];
                    d4 += blo(hv.z) * wr[4]; d5 += bhi(hv.z) * wr[5];
                    d6 += blo(hv.w) * wr[6]; d7 += bhi(hv.w) * wr[7];
                }
            uint4 pk;
            pk.x = (unsigned)f2bf(d0) | ((unsigned)f2bf(d1) << 16);
            pk.y = (unsigned)f2bf(d2) | ((unsigned)f2bf(d3) << 16);
            pk.z = (unsigned)f2bf(d4) | ((unsigned)f2bf(d5) << 16);
            pk.w = (unsigned)f2bf(d6) | ((unsigned)f2bf(d7) << 16);
            *(uint4*)&dwa[p * 72 + c8] = pk;
        }
        __syncthreads();
        // ---- Phase B: pointwise via MFMA
#pragma unroll
        for (int ks = 0; ks < 2; ++ks)
#pragma unroll
            for (int mt = 0; mt < 4; ++mt) {
                s16x8 af = *(const s16x8*)&dwa[(mt * 16 + (lane & 15)) * 72 +
                                               ks * 32 + ((lane >> 4) << 3)];
                acc[mt] = __builtin_amdgcn_mfma_f32_16x16x32_bf16(
                    af, bfr[ks], acc[mt], 0, 0, 0);
            }
    }
    // ---- epilogue: C-layout col=lane&15, row=(lane>>4)*4+i
    const int col = lane & 15;
    const int rq = (lane >> 4) << 2;
#pragma unroll
    for (int mt = 0; mt < 4; ++mt)
#pragma unroll
        for (int i = 0; i < 4; ++i) {
            int m = mt * 16 + rq + i;
            out[((b * HW + h0 + (m >> 3)) * HW + (w0 + (m & 7))) * 128 +
                (g << 6) + fb + col] = acc[mt][i];
        }
}

extern "C" void kernel_launch(void* const* d_in, const int* in_sizes, int n_in,
                              void* d_out, int out_size, void* d_ws,
                              size_t ws_size, hipStream_t stream) {
    const float* x = (const float*)d_in[0];
    const float* off_w = (const float*)d_in[1];
    const float* off_b = (const float*)d_in[2];
    const float* dw_w = (const float*)d_in[3];
    const float* dw_b = (const float*)d_in[4];
    const float* pw_w = (const float*)d_in[5];
    const float* pw_b = (const float*)d_in[6];

    float* wsf = (float*)d_ws;
    float* off_ws = wsf;                                           // 37.75 MB
    unsigned short* pwt = (unsigned short*)(wsf + OFF_WS_FLOATS);  // 147 KB
    float* bias2 = wsf + OFF_WS_FLOATS + 36864;                    // 512 B

    bias_kernel<<<dim3(GNUM), dim3(64), 0, stream>>>(pw_w, pw_b, dw_b, bias2);
    pw_prep<<<dim3(9, GNUM), dim3(256), 0, stream>>>(pw_w, pwt);
    offset_kernel<<<dim3(64, BATCH, GNUM * 2), dim3(256), 0, stream>>>(
        x, off_w, off_b, off_ws);
    deform_kernel<<<dim3(256, BATCH, GNUM), dim3(256), 0, stream>>>(
        x, off_ws, off_b, dw_w, pwt, bias2, (float*)d_out);
}

// Round 5
// 308.123 us; speedup vs baseline: 3.2578x; 1.6458x over previous
//
#include <hip/hip_runtime.h>

#define HW 128
#define GNUM 2
#define BATCH 4
#define BHW2 (BATCH * HW * HW)                 // 65536
#define OFF_WS_FLOATS (GNUM * 18 * BHW2)       // planar [g*18+o][b][pix]
#define OBT_STRIDE (GNUM * 18 * 2 * 512)       // shorts per hi/lo sub-buffer
#define PWT_FLOATS 36864                       // 73728 shorts
#define OBT_FLOATS 36864                       // 73728 shorts (hi+lo)

typedef short s16x8 __attribute__((ext_vector_type(8)));
typedef float f32x4 __attribute__((ext_vector_type(4)));

__device__ inline unsigned short f2bf(float f) {
    union { float f; unsigned u; } v;
    v.f = f;
    unsigned r = (v.u + 0x7fffu + ((v.u >> 16) & 1u)) >> 16;
    return (unsigned short)r;
}
__device__ inline float blo(unsigned u) {
    union { unsigned u; float f; } v; v.u = u << 16; return v.f;
}
__device__ inline float bhi(unsigned u) {
    union { unsigned u; float f; } v; v.u = u & 0xffff0000u; return v.f;
}

// ---------------------------------------------------------------------------
// bias_kernel: bias2[g][f] = pw_b[g,f] + sum_kin pw_w[g,kin,f]*dw_b[g,kin]
// ---------------------------------------------------------------------------
__global__ void bias_kernel(const float* __restrict__ pw_w,
                            const float* __restrict__ pw_b,
                            const float* __restrict__ dw_b,
                            float* __restrict__ bias2) {
    int g = blockIdx.x;
    int f = threadIdx.x;
    float acc = pw_b[g * 64 + f];
    for (int kin = 0; kin < 576; ++kin)
        acc += pw_w[(g * 576 + kin) * 64 + f] * dw_b[g * 576 + kin];
    bias2[g * 64 + f] = acc;
}

// ---------------------------------------------------------------------------
// pw_prep: pw_w -> bf16 B-fragment order for mfma 16x16x32 (validated R2/R3).
// lane l holds B[k=(l>>4)*8+i][n=l&15], f = wv*16+n, kin = j*64+ks*32+k.
// ---------------------------------------------------------------------------
__global__ __launch_bounds__(256) void pw_prep(const float* __restrict__ pw_w,
                                               unsigned short* __restrict__ pwt) {
    const int j = blockIdx.x, g = blockIdx.y;
    const int t = threadIdx.x;
    const int wv = t >> 6, lane = t & 63;
    const int f = wv * 16 + (lane & 15);
    const int kbase = (lane >> 4) << 3;
#pragma unroll
    for (int ks = 0; ks < 2; ++ks)
#pragma unroll
        for (int i = 0; i < 8; ++i) {
            int kin = j * 64 + ks * 32 + kbase + i;
            pwt[((((g * 9 + j) * 4 + wv) * 2 + ks) << 9) + lane * 8 + i] =
                f2bf(pw_w[(g * 576 + kin) * 64 + f]);
        }
}

// ---------------------------------------------------------------------------
// ow_prep: off_w -> bf16 hi/lo B-fragments for the offset-conv MFMA.
// k-step s (0..17): tap = s>>1, c = (s&1)*32 + k.  n-tile nt: n = nt*16+col.
// obt[hi] at idx, obt[lo] at OBT_STRIDE + idx.
// ---------------------------------------------------------------------------
__global__ __launch_bounds__(256) void ow_prep(const float* __restrict__ off_w,
                                               unsigned short* __restrict__ obt) {
    const int s = blockIdx.x, g = blockIdx.y;
    const int tap = s >> 1;
    for (int e = threadIdx.x; e < 1024; e += 256) {
        int nt = e >> 9, le = e & 511;
        int lane = le >> 3, i = le & 7;
        int k = ((lane >> 4) << 3) + i;
        int c = ((s & 1) << 5) + k;
        int n = (nt << 4) + (lane & 15);
        float v = (n < 18) ? off_w[((g * 9 + tap) * 64 + c) * 18 + n] : 0.f;
        unsigned short hi = f2bf(v);
        unsigned short lo = f2bf(v - blo(hi));
        int idx = (((g * 18 + s) * 2 + nt) << 9) + le;
        obt[idx] = hi;
        obt[OBT_STRIDE + idx] = lo;
    }
}

// ---------------------------------------------------------------------------
// offset_mfma: 3x3 SAME conv 64->18 via bf16 MFMA, split-precision (3
// products: AhBh + AlBh + AhBl) so offsets stay ~fp32-accurate.
// Block = 256 thr = 16x16 px tile of one (b,g).  Two 32-channel passes;
// xh[sp][0..31]=hi, [32..63]=lo, stride 72 shorts (46.7 KB LDS).
// Output planar: off_ws[(g*18+o)*BHW2 + b*HW*HW + pix]  (+ off_b folded in).
// ---------------------------------------------------------------------------
__global__ __launch_bounds__(256) void offset_mfma(
    const float* __restrict__ x, const unsigned short* __restrict__ obt,
    const float* __restrict__ off_b, float* __restrict__ off_ws) {
    __shared__ unsigned short xh[324 * 72];
    const int tileIdx = blockIdx.x;
    const int b = blockIdx.y, g = blockIdx.z;
    const int h0 = (tileIdx >> 3) << 4, w0 = (tileIdx & 7) << 4;
    const int t = threadIdx.x;
    const int lane = t & 63;
    const int wv = __builtin_amdgcn_readfirstlane(t >> 6);
    const int px = lane & 15;
    const int kq = (lane >> 4) << 3;

    f32x4 acc[4][2];
    {
        const int col = lane & 15;
        float b0 = (col < 18) ? off_b[g * 18 + col] : 0.f;
        float b1 = (col + 16 < 18) ? off_b[g * 18 + col + 16] : 0.f;
#pragma unroll
        for (int mt = 0; mt < 4; ++mt) {
            acc[mt][0] = (f32x4){b0, b0, b0, b0};
            acc[mt][1] = (f32x4){b1, b1, b1, b1};
        }
    }
    for (int q = 0; q < 2; ++q) {
        if (q) __syncthreads();
        // stage halo 18x18 x 32ch (this q-half), fp32 -> hi/lo bf16
        for (int idx = t; idx < 324 * 8; idx += 256) {
            int sp = idx >> 3, cq = idx & 7;
            int sy = sp / 18, sx = sp - sy * 18;
            int gy = h0 - 1 + sy, gx = w0 - 1 + sx;
            ushort4 h4 = {0, 0, 0, 0}, l4 = {0, 0, 0, 0};
            if ((unsigned)gy < HW && (unsigned)gx < HW) {
                const float4 v = *(const float4*)&x[(((b * HW + gy) * HW + gx)
                                                    << 7) +
                                                   (g << 6) + (q << 5) + (cq << 2)];
                h4.x = f2bf(v.x); l4.x = f2bf(v.x - blo(h4.x));
                h4.y = f2bf(v.y); l4.y = f2bf(v.y - blo(h4.y));
                h4.z = f2bf(v.z); l4.z = f2bf(v.z - blo(h4.z));
                h4.w = f2bf(v.w); l4.w = f2bf(v.w - blo(h4.w));
            }
            *(ushort4*)&xh[sp * 72 + (cq << 2)] = h4;
            *(ushort4*)&xh[sp * 72 + 32 + (cq << 2)] = l4;
        }
        __syncthreads();
        for (int tap = 0; tap < 9; ++tap) {
            const int s = (tap << 1) + q;
            const int ky = tap / 3, kx = tap - ky * 3;
            const int bidx = ((g * 18 + s) << 1) << 9;
            s16x8 bh0 = *(const s16x8*)&obt[bidx + lane * 8];
            s16x8 bh1 = *(const s16x8*)&obt[bidx + 512 + lane * 8];
            s16x8 bl0 = *(const s16x8*)&obt[OBT_STRIDE + bidx + lane * 8];
            s16x8 bl1 = *(const s16x8*)&obt[OBT_STRIDE + bidx + 512 + lane * 8];
#pragma unroll
            for (int mt = 0; mt < 4; ++mt) {
                const int py = (wv << 2) + mt;
                const int base = ((py + ky) * 18 + px + kx) * 72;
                s16x8 ah = *(const s16x8*)&xh[base + kq];
                s16x8 al = *(const s16x8*)&xh[base + 32 + kq];
                acc[mt][0] = __builtin_amdgcn_mfma_f32_16x16x32_bf16(
                    ah, bh0, acc[mt][0], 0, 0, 0);
                acc[mt][1] = __builtin_amdgcn_mfma_f32_16x16x32_bf16(
                    ah, bh1, acc[mt][1], 0, 0, 0);
                acc[mt][0] = __builtin_amdgcn_mfma_f32_16x16x32_bf16(
                    al, bh0, acc[mt][0], 0, 0, 0);
                acc[mt][1] = __builtin_amdgcn_mfma_f32_16x16x32_bf16(
                    al, bh1, acc[mt][1], 0, 0, 0);
                acc[mt][0] = __builtin_amdgcn_mfma_f32_16x16x32_bf16(
                    ah, bl0, acc[mt][0], 0, 0, 0);
                acc[mt][1] = __builtin_amdgcn_mfma_f32_16x16x32_bf16(
                    ah, bl1, acc[mt][1], 0, 0, 0);
            }
        }
    }
    // epilogue: C row = (lane>>4)*4+i = px_out, col = lane&15 = n
    const int col = lane & 15;
    const int rq = (lane >> 4) << 2;
#pragma unroll
    for (int mt = 0; mt < 4; ++mt) {
        const int py = (wv << 2) + mt;
        const int pixrow = (b * HW + h0 + py) * HW + w0;
#pragma unroll
        for (int nt = 0; nt < 2; ++nt) {
            int o = (nt << 4) + col;
            if (o < 18)
                *(f32x4*)&off_ws[(g * 18 + o) * BHW2 + pixrow + rq] =
                    acc[mt][nt];
        }
    }
}

// ---------------------------------------------------------------------------
// deform_kernel: W (per-tap bilinear weights, once per sample position) ->
// S (gather) -> A (depthwise) -> B (pointwise MFMA).  3 barriers/tap.
//   samp: 100x72 bf16 (14.4 KB)   dwa: 64x72 bf16 (9.2 KB)
//   wlw:  float4[100] weights     wli: int4[100] {base, dxo, dyo, -}
// ---------------------------------------------------------------------------
__global__ __launch_bounds__(256) void deform_kernel(
    const float* __restrict__ x, const float* __restrict__ off_ws,
    const float* __restrict__ dw_w, const unsigned short* __restrict__ pwt,
    const float* __restrict__ bias2, float* __restrict__ out) {
    __shared__ unsigned short samp[100 * 72];
    __shared__ unsigned short dwa[64 * 72];
    __shared__ float4 wlw[100];
    __shared__ int4 wli[100];
    const int tileIdx = blockIdx.x;
    const int b = blockIdx.y, g = blockIdx.z;
    const int h0 = (tileIdx >> 4) << 3, w0 = (tileIdx & 15) << 3;
    const int t = threadIdx.x;
    const int lane = t & 63;
    const int wv = __builtin_amdgcn_readfirstlane(t >> 6);
    const int fb = wv << 4;
    const int p = lane;
    const int ayp = p >> 3, axp = p & 7;
    const int gcl = (g << 6) + lane;

    const float bs = bias2[g * 64 + fb + (lane & 15)];
    f32x4 acc[4];
#pragma unroll
    for (int mt = 0; mt < 4; ++mt) acc[mt] = (f32x4){bs, bs, bs, bs};

    for (int j = 0; j < 9; ++j) {
        const int jy = j / 3, jx = j - jy * 3;
        s16x8 bfr[2];
#pragma unroll
        for (int ks = 0; ks < 2; ++ks)
            bfr[ks] = *(const s16x8*)&pwt[((((g * 9 + j) * 4 + wv) * 2 + ks)
                                           << 9) + lane * 8];
        // ---- Phase W: bilinear weights + corner offsets, one thread per sp
        if (t < 100) {
            const int sp = t;
            const int spy = sp / 10, spx = sp - spy * 10;
            const int gy = h0 - 1 + spy, gx = w0 - 1 + spx;
            float4 w4 = {0.f, 0.f, 0.f, 0.f};
            int4 ii = {b << 21, 0, 0, 0};
            if ((unsigned)gy < HW && (unsigned)gx < HW) {
                const int pix = b * (HW * HW) + gy * HW + gx;
                const float ox = off_ws[(g * 18 + 2 * j) * BHW2 + pix];
                const float oy = off_ws[(g * 18 + 2 * j + 1) * BHW2 + pix];
                float xf = fminf(fmaxf((float)(gx + jx - 1) + ox, 0.f), 127.f);
                float yf = fminf(fmaxf((float)(gy + jy - 1) + oy, 0.f), 127.f);
                float x0 = floorf(xf), y0 = floorf(yf);
                float x1 = fminf(x0 + 1.f, 127.f);
                float y1 = fminf(y0 + 1.f, 127.f);
                w4.x = (x1 - xf) * (y1 - yf);   // (y0,x0)
                w4.y = (x1 - xf) * (yf - y0);   // (y1,x0)
                w4.z = (xf - x0) * (y1 - yf);   // (y0,x1)
                w4.w = (xf - x0) * (yf - y0);   // (y1,x1)
                const int x0i = (int)x0, y0i = (int)y0;
                ii.x = ((b * HW + y0i) * HW + x0i) << 7;
                ii.y = ((int)x1 - x0i) << 7;    // dx in elements
                ii.z = ((int)y1 - y0i) << 14;   // dy in elements
            }
            wlw[sp] = w4;
            wli[sp] = ii;
        }
        __syncthreads();
        // ---- Phase S: gather (sp wave-uniform, lane = channel)
        for (int k = 0; k < 25; ++k) {
            const int sp = wv + (k << 2);
            const float4 w4 = wlw[sp];
            const int4 ii = wli[sp];
            const int pa = ii.x + gcl;
            const float va = x[pa];
            const float vb = x[pa + ii.z];
            const float vc = x[pa + ii.y];
            const float vd = x[pa + ii.y + ii.z];
            samp[sp * 72 + lane] =
                f2bf(w4.x * va + w4.y * vb + w4.z * vc + w4.w * vd);
        }
        __syncthreads();
        // ---- Phase A: depthwise 3x3, channels [fb, fb+16), bf16 in/out
#pragma unroll
        for (int cq = 0; cq < 2; ++cq) {
            const int c8 = fb + (cq << 3);
            float d0 = 0.f, d1 = 0.f, d2 = 0.f, d3 = 0.f;
            float d4 = 0.f, d5 = 0.f, d6 = 0.f, d7 = 0.f;
#pragma unroll
            for (int ky = 0; ky < 3; ++ky)
#pragma unroll
                for (int kx = 0; kx < 3; ++kx) {
                    const uint4 hv = *(const uint4*)&samp
                        [((ayp + ky) * 10 + axp + kx) * 72 + c8];
                    const float* wr =
                        &dw_w[((g * 3 + ky) * 3 + kx) * 576 + (j << 6) + c8];
                    d0 += blo(hv.x) * wr[0]; d1 += bhi(hv.x) * wr[1];
                    d2 += blo(hv.y) * wr[2]; d3 += bhi(hv.y) * wr[3];
                    d4 += blo(hv.z) * wr[4]; d5 += bhi(hv.z) * wr[5];
                    d6 += blo(hv.w) * wr[6]; d7 += bhi(hv.w) * wr[7];
                }
            uint4 pk;
            pk.x = (unsigned)f2bf(d0) | ((unsigned)f2bf(d1) << 16);
            pk.y = (unsigned)f2bf(d2) | ((unsigned)f2bf(d3) << 16);
            pk.z = (unsigned)f2bf(d4) | ((unsigned)f2bf(d5) << 16);
            pk.w = (unsigned)f2bf(d6) | ((unsigned)f2bf(d7) << 16);
            *(uint4*)&dwa[p * 72 + c8] = pk;
        }
        __syncthreads();
        // ---- Phase B: pointwise via MFMA
#pragma unroll
        for (int ks = 0; ks < 2; ++ks)
#pragma unroll
            for (int mt = 0; mt < 4; ++mt) {
                s16x8 af = *(const s16x8*)&dwa[(mt * 16 + (lane & 15)) * 72 +
                                               ks * 32 + ((lane >> 4) << 3)];
                acc[mt] = __builtin_amdgcn_mfma_f32_16x16x32_bf16(
                    af, bfr[ks], acc[mt], 0, 0, 0);
            }
    }
    // ---- epilogue: C-layout col=lane&15, row=(lane>>4)*4+i
    const int col = lane & 15;
    const int rq = (lane >> 4) << 2;
#pragma unroll
    for (int mt = 0; mt < 4; ++mt)
#pragma unroll
        for (int i = 0; i < 4; ++i) {
            int m = mt * 16 + rq + i;
            out[((b * HW + h0 + (m >> 3)) * HW + (w0 + (m & 7))) * 128 +
                (g << 6) + fb + col] = acc[mt][i];
        }
}

extern "C" void kernel_launch(void* const* d_in, const int* in_sizes, int n_in,
                              void* d_out, int out_size, void* d_ws,
                              size_t ws_size, hipStream_t stream) {
    const float* x = (const float*)d_in[0];
    const float* off_w = (const float*)d_in[1];
    const float* off_b = (const float*)d_in[2];
    const float* dw_w = (const float*)d_in[3];
    const float* dw_b = (const float*)d_in[4];
    const float* pw_w = (const float*)d_in[5];
    const float* pw_b = (const float*)d_in[6];

    // workspace layout (floats): [off_ws | pwt | obt | bias2]
    float* wsf = (float*)d_ws;
    float* off_ws = wsf;                                        // 9.44 MB
    unsigned short* pwt =
        (unsigned short*)(wsf + OFF_WS_FLOATS);                 // 147456 B
    unsigned short* obt =
        (unsigned short*)(wsf + OFF_WS_FLOATS + PWT_FLOATS);    // 147456 B
    float* bias2 = wsf + OFF_WS_FLOATS + PWT_FLOATS + OBT_FLOATS;  // 512 B

    bias_kernel<<<dim3(GNUM), dim3(64), 0, stream>>>(pw_w, pw_b, dw_b, bias2);
    pw_prep<<<dim3(9, GNUM), dim3(256), 0, stream>>>(pw_w, pwt);
    ow_prep<<<dim3(18, GNUM), dim3(256), 0, stream>>>(off_w, obt);
    offset_mfma<<<dim3(64, BATCH, GNUM), dim3(256), 0, stream>>>(
        x, obt, off_b, off_ws);
    deform_kernel<<<dim3(256, BATCH, GNUM), dim3(256), 0, stream>>>(
        x, off_ws, dw_w, pwt, bias2, (float*)d_out);
}

// Round 6
// 255.302 us; speedup vs baseline: 3.9319x; 1.2069x over previous
//
#include <hip/hip_runtime.h>

#define HW 128
#define GNUM 2
#define BATCH 4
#define BHW2 (BATCH * HW * HW)                 // 65536
#define OFF_WS_FLOATS (GNUM * 18 * BHW2)       // planar [g*18+o][b][pix]
#define OBT_STRIDE (GNUM * 18 * 2 * 512)       // shorts per hi/lo sub-buffer
#define PWT_FLOATS 36864                       // 73728 shorts
#define OBT_FLOATS 36864                       // 73728 shorts (hi+lo)

typedef short s16x8 __attribute__((ext_vector_type(8)));
typedef float f32x4 __attribute__((ext_vector_type(4)));

__device__ inline unsigned short f2bf(float f) {
    union { float f; unsigned u; } v;
    v.f = f;
    unsigned r = (v.u + 0x7fffu + ((v.u >> 16) & 1u)) >> 16;
    return (unsigned short)r;
}
__device__ inline float blo(unsigned u) {
    union { unsigned u; float f; } v; v.u = u << 16; return v.f;
}
__device__ inline float bhi(unsigned u) {
    union { unsigned u; float f; } v; v.u = u & 0xffff0000u; return v.f;
}

// ---------------------------------------------------------------------------
// pw_prep: pw_w -> bf16 B-fragment order for mfma 16x16x32 (validated R2-R5)
// + folded bias partial: bias2[g][f] += sum_kin pw_w[kin][f]*dw_b[kin]
// (bias2 pre-zeroed; pw_b added by deform at read time).
// ---------------------------------------------------------------------------
__global__ __launch_bounds__(256) void pw_prep(const float* __restrict__ pw_w,
                                               const float* __restrict__ dw_b,
                                               unsigned short* __restrict__ pwt,
                                               float* __restrict__ bias2) {
    const int j = blockIdx.x, g = blockIdx.y;
    const int t = threadIdx.x;
    const int wv = t >> 6, lane = t & 63;
    const int f = wv * 16 + (lane & 15);
    const int kbase = (lane >> 4) << 3;
    float part = 0.f;
#pragma unroll
    for (int ks = 0; ks < 2; ++ks)
#pragma unroll
        for (int i = 0; i < 8; ++i) {
            int kin = j * 64 + ks * 32 + kbase + i;
            float v = pw_w[(g * 576 + kin) * 64 + f];
            pwt[((((g * 9 + j) * 4 + wv) * 2 + ks) << 9) + lane * 8 + i] =
                f2bf(v);
            part += v * dw_b[g * 576 + kin];
        }
    atomicAdd(&bias2[g * 64 + f], part);
}

// ---------------------------------------------------------------------------
// ow_prep: off_w -> bf16 hi/lo B-fragments for the offset-conv MFMA.
// ---------------------------------------------------------------------------
__global__ __launch_bounds__(256) void ow_prep(const float* __restrict__ off_w,
                                               unsigned short* __restrict__ obt) {
    const int s = blockIdx.x, g = blockIdx.y;
    const int tap = s >> 1;
    for (int e = threadIdx.x; e < 1024; e += 256) {
        int nt = e >> 9, le = e & 511;
        int lane = le >> 3, i = le & 7;
        int k = ((lane >> 4) << 3) + i;
        int c = ((s & 1) << 5) + k;
        int n = (nt << 4) + (lane & 15);
        float v = (n < 18) ? off_w[((g * 9 + tap) * 64 + c) * 18 + n] : 0.f;
        unsigned short hi = f2bf(v);
        unsigned short lo = f2bf(v - blo(hi));
        int idx = (((g * 18 + s) * 2 + nt) << 9) + le;
        obt[idx] = hi;
        obt[OBT_STRIDE + idx] = lo;
    }
}

// ---------------------------------------------------------------------------
// offset_mfma: 3x3 SAME conv 64->18 via bf16 MFMA, split-precision
// (AhBh + AlBh + AhBl).  Unchanged from R5 (validated).
// ---------------------------------------------------------------------------
__global__ __launch_bounds__(256) void offset_mfma(
    const float* __restrict__ x, const unsigned short* __restrict__ obt,
    const float* __restrict__ off_b, float* __restrict__ off_ws) {
    __shared__ unsigned short xh[324 * 72];
    const int tileIdx = blockIdx.x;
    const int b = blockIdx.y, g = blockIdx.z;
    const int h0 = (tileIdx >> 3) << 4, w0 = (tileIdx & 7) << 4;
    const int t = threadIdx.x;
    const int lane = t & 63;
    const int wv = __builtin_amdgcn_readfirstlane(t >> 6);
    const int px = lane & 15;
    const int kq = (lane >> 4) << 3;

    f32x4 acc[4][2];
    {
        const int col = lane & 15;
        float b0 = (col < 18) ? off_b[g * 18 + col] : 0.f;
        float b1 = (col + 16 < 18) ? off_b[g * 18 + col + 16] : 0.f;
#pragma unroll
        for (int mt = 0; mt < 4; ++mt) {
            acc[mt][0] = (f32x4){b0, b0, b0, b0};
            acc[mt][1] = (f32x4){b1, b1, b1, b1};
        }
    }
    for (int q = 0; q < 2; ++q) {
        if (q) __syncthreads();
        for (int idx = t; idx < 324 * 8; idx += 256) {
            int sp = idx >> 3, cq = idx & 7;
            int sy = sp / 18, sx = sp - sy * 18;
            int gy = h0 - 1 + sy, gx = w0 - 1 + sx;
            ushort4 h4 = {0, 0, 0, 0}, l4 = {0, 0, 0, 0};
            if ((unsigned)gy < HW && (unsigned)gx < HW) {
                const float4 v = *(const float4*)&x[(((b * HW + gy) * HW + gx)
                                                    << 7) +
                                                   (g << 6) + (q << 5) + (cq << 2)];
                h4.x = f2bf(v.x); l4.x = f2bf(v.x - blo(h4.x));
                h4.y = f2bf(v.y); l4.y = f2bf(v.y - blo(h4.y));
                h4.z = f2bf(v.z); l4.z = f2bf(v.z - blo(h4.z));
                h4.w = f2bf(v.w); l4.w = f2bf(v.w - blo(h4.w));
            }
            *(ushort4*)&xh[sp * 72 + (cq << 2)] = h4;
            *(ushort4*)&xh[sp * 72 + 32 + (cq << 2)] = l4;
        }
        __syncthreads();
        for (int tap = 0; tap < 9; ++tap) {
            const int s = (tap << 1) + q;
            const int ky = tap / 3, kx = tap - ky * 3;
            const int bidx = ((g * 18 + s) << 1) << 9;
            s16x8 bh0 = *(const s16x8*)&obt[bidx + lane * 8];
            s16x8 bh1 = *(const s16x8*)&obt[bidx + 512 + lane * 8];
            s16x8 bl0 = *(const s16x8*)&obt[OBT_STRIDE + bidx + lane * 8];
            s16x8 bl1 = *(const s16x8*)&obt[OBT_STRIDE + bidx + 512 + lane * 8];
#pragma unroll
            for (int mt = 0; mt < 4; ++mt) {
                const int py = (wv << 2) + mt;
                const int base = ((py + ky) * 18 + px + kx) * 72;
                s16x8 ah = *(const s16x8*)&xh[base + kq];
                s16x8 al = *(const s16x8*)&xh[base + 32 + kq];
                acc[mt][0] = __builtin_amdgcn_mfma_f32_16x16x32_bf16(
                    ah, bh0, acc[mt][0], 0, 0, 0);
                acc[mt][1] = __builtin_amdgcn_mfma_f32_16x16x32_bf16(
                    ah, bh1, acc[mt][1], 0, 0, 0);
                acc[mt][0] = __builtin_amdgcn_mfma_f32_16x16x32_bf16(
                    al, bh0, acc[mt][0], 0, 0, 0);
                acc[mt][1] = __builtin_amdgcn_mfma_f32_16x16x32_bf16(
                    al, bh1, acc[mt][1], 0, 0, 0);
                acc[mt][0] = __builtin_amdgcn_mfma_f32_16x16x32_bf16(
                    ah, bl0, acc[mt][0], 0, 0, 0);
                acc[mt][1] = __builtin_amdgcn_mfma_f32_16x16x32_bf16(
                    ah, bl1, acc[mt][1], 0, 0, 0);
            }
        }
    }
    const int col = lane & 15;
    const int rq = (lane >> 4) << 2;
#pragma unroll
    for (int mt = 0; mt < 4; ++mt) {
        const int py = (wv << 2) + mt;
        const int pixrow = (b * HW + h0 + py) * HW + w0;
#pragma unroll
        for (int nt = 0; nt < 2; ++nt) {
            int o = (nt << 4) + col;
            if (o < 18)
                *(f32x4*)&off_ws[(g * 18 + o) * BHW2 + pixrow + rq] =
                    acc[mt][nt];
        }
    }
}

// ---------------------------------------------------------------------------
// deform_kernel: W -> S (float4 gather, 16 lanes/sample) -> A (depthwise) ->
// B (pointwise MFMA).  3 barriers/tap.  __launch_bounds__(256,6): target
// <=84 VGPR so 6 blocks/CU (LDS 27.1 KB also allows 6).
// ---------------------------------------------------------------------------
__global__ __launch_bounds__(256, 6) void deform_kernel(
    const float* __restrict__ x, const float* __restrict__ off_ws,
    const float* __restrict__ dw_w, const unsigned short* __restrict__ pwt,
    const float* __restrict__ bias2, const float* __restrict__ pw_b,
    float* __restrict__ out) {
    __shared__ unsigned short samp[100 * 72];
    __shared__ unsigned short dwa[64 * 72];
    __shared__ float4 wlw[100];
    __shared__ int4 wli[100];
    const int tileIdx = blockIdx.x;
    const int b = blockIdx.y, g = blockIdx.z;
    const int h0 = (tileIdx >> 4) << 3, w0 = (tileIdx & 15) << 3;
    const int t = threadIdx.x;
    const int lane = t & 63;
    const int wv = __builtin_amdgcn_readfirstlane(t >> 6);
    const int fb = wv << 4;
    const int p = lane;
    const int ayp = p >> 3, axp = p & 7;
    const int grp = t >> 4, sl = t & 15;   // 16-lane gather groups

    const float bs = bias2[g * 64 + fb + (lane & 15)] +
                     pw_b[g * 64 + fb + (lane & 15)];
    f32x4 acc[4];
#pragma unroll
    for (int mt = 0; mt < 4; ++mt) acc[mt] = (f32x4){bs, bs, bs, bs};

    for (int j = 0; j < 9; ++j) {
        const int jy = j / 3, jx = j - jy * 3;
        s16x8 bfr[2];
#pragma unroll
        for (int ks = 0; ks < 2; ++ks)
            bfr[ks] = *(const s16x8*)&pwt[((((g * 9 + j) * 4 + wv) * 2 + ks)
                                           << 9) + lane * 8];
        // ---- Phase W: bilinear weights + corner offsets, one thread per sp
        if (t < 100) {
            const int sp = t;
            const int spy = sp / 10, spx = sp - spy * 10;
            const int gy = h0 - 1 + spy, gx = w0 - 1 + spx;
            float4 w4 = {0.f, 0.f, 0.f, 0.f};
            int4 ii = {b << 21, 0, 0, 0};
            if ((unsigned)gy < HW && (unsigned)gx < HW) {
                const int pix = b * (HW * HW) + gy * HW + gx;
                const float ox = off_ws[(g * 18 + 2 * j) * BHW2 + pix];
                const float oy = off_ws[(g * 18 + 2 * j + 1) * BHW2 + pix];
                float xf = fminf(fmaxf((float)(gx + jx - 1) + ox, 0.f), 127.f);
                float yf = fminf(fmaxf((float)(gy + jy - 1) + oy, 0.f), 127.f);
                float x0 = floorf(xf), y0 = floorf(yf);
                float x1 = fminf(x0 + 1.f, 127.f);
                float y1 = fminf(y0 + 1.f, 127.f);
                w4.x = (x1 - xf) * (y1 - yf);   // (y0,x0)
                w4.y = (x1 - xf) * (yf - y0);   // (y1,x0)
                w4.z = (xf - x0) * (y1 - yf);   // (y0,x1)
                w4.w = (xf - x0) * (yf - y0);   // (y1,x1)
                const int x0i = (int)x0, y0i = (int)y0;
                ii.x = ((b * HW + y0i) * HW + x0i) << 7;
                ii.y = ((int)x1 - x0i) << 7;    // dx in elements
                ii.z = ((int)y1 - y0i) << 14;   // dy in elements
            }
            wlw[sp] = w4;
            wli[sp] = ii;
        }
        __syncthreads();
        // ---- Phase S: float4 gather; 16 sample positions per iteration,
        // 16 lanes per position (4 channels each).
        for (int it = 0; it < 7; ++it) {
            const int sp = (it << 4) + grp;
            if (sp < 100) {
                const float4 w4 = wlw[sp];
                const int4 ii = wli[sp];
                const float* xa = x + ii.x + (g << 6) + (sl << 2);
                const float4 va = *(const float4*)xa;
                const float4 vb = *(const float4*)(xa + ii.z);
                const float4 vc = *(const float4*)(xa + ii.y);
                const float4 vd = *(const float4*)(xa + ii.y + ii.z);
                float r0 = w4.x * va.x + w4.y * vb.x + w4.z * vc.x + w4.w * vd.x;
                float r1 = w4.x * va.y + w4.y * vb.y + w4.z * vc.y + w4.w * vd.y;
                float r2 = w4.x * va.z + w4.y * vb.z + w4.z * vc.z + w4.w * vd.z;
                float r3 = w4.x * va.w + w4.y * vb.w + w4.z * vc.w + w4.w * vd.w;
                uint2 pk;
                pk.x = (unsigned)f2bf(r0) | ((unsigned)f2bf(r1) << 16);
                pk.y = (unsigned)f2bf(r2) | ((unsigned)f2bf(r3) << 16);
                *(uint2*)&samp[sp * 72 + (sl << 2)] = pk;
            }
        }
        __syncthreads();
        // ---- Phase A: depthwise 3x3, channels [fb, fb+16), bf16 in/out
#pragma unroll
        for (int cq = 0; cq < 2; ++cq) {
            const int c8 = fb + (cq << 3);
            float d0 = 0.f, d1 = 0.f, d2 = 0.f, d3 = 0.f;
            float d4 = 0.f, d5 = 0.f, d6 = 0.f, d7 = 0.f;
#pragma unroll
            for (int ky = 0; ky < 3; ++ky)
#pragma unroll
                for (int kx = 0; kx < 3; ++kx) {
                    const uint4 hv = *(const uint4*)&samp
                        [((ayp + ky) * 10 + axp + kx) * 72 + c8];
                    const float* wr =
                        &dw_w[((g * 3 + ky) * 3 + kx) * 576 + (j << 6) + c8];
                    d0 += blo(hv.x) * wr[0]; d1 += bhi(hv.x) * wr[1];
                    d2 += blo(hv.y) * wr[2]; d3 += bhi(hv.y) * wr[3];
                    d4 += blo(hv.z) * wr[4]; d5 += bhi(hv.z) * wr[5];
                    d6 += blo(hv.w) * wr[6]; d7 += bhi(hv.w) * wr[7];
                }
            uint4 pk;
            pk.x = (unsigned)f2bf(d0) | ((unsigned)f2bf(d1) << 16);
            pk.y = (unsigned)f2bf(d2) | ((unsigned)f2bf(d3) << 16);
            pk.z = (unsigned)f2bf(d4) | ((unsigned)f2bf(d5) << 16);
            pk.w = (unsigned)f2bf(d6) | ((unsigned)f2bf(d7) << 16);
            *(uint4*)&dwa[p * 72 + c8] = pk;
        }
        __syncthreads();
        // ---- Phase B: pointwise via MFMA
#pragma unroll
        for (int ks = 0; ks < 2; ++ks)
#pragma unroll
            for (int mt = 0; mt < 4; ++mt) {
                s16x8 af = *(const s16x8*)&dwa[(mt * 16 + (lane & 15)) * 72 +
                                               ks * 32 + ((lane >> 4) << 3)];
                acc[mt] = __builtin_amdgcn_mfma_f32_16x16x32_bf16(
                    af, bfr[ks], acc[mt], 0, 0, 0);
            }
    }
    // ---- epilogue: C-layout col=lane&15, row=(lane>>4)*4+i
    const int col = lane & 15;
    const int rq = (lane >> 4) << 2;
#pragma unroll
    for (int mt = 0; mt < 4; ++mt)
#pragma unroll
        for (int i = 0; i < 4; ++i) {
            int m = mt * 16 + rq + i;
            out[((b * HW + h0 + (m >> 3)) * HW + (w0 + (m & 7))) * 128 +
                (g << 6) + fb + col] = acc[mt][i];
        }
}

extern "C" void kernel_launch(void* const* d_in, const int* in_sizes, int n_in,
                              void* d_out, int out_size, void* d_ws,
                              size_t ws_size, hipStream_t stream) {
    const float* x = (const float*)d_in[0];
    const float* off_w = (const float*)d_in[1];
    const float* off_b = (const float*)d_in[2];
    const float* dw_w = (const float*)d_in[3];
    const float* dw_b = (const float*)d_in[4];
    const float* pw_w = (const float*)d_in[5];
    const float* pw_b = (const float*)d_in[6];

    // workspace layout (floats): [off_ws | pwt | obt | bias2]
    float* wsf = (float*)d_ws;
    float* off_ws = wsf;                                        // 9.44 MB
    unsigned short* pwt =
        (unsigned short*)(wsf + OFF_WS_FLOATS);                 // 147456 B
    unsigned short* obt =
        (unsigned short*)(wsf + OFF_WS_FLOATS + PWT_FLOATS);    // 147456 B
    float* bias2 = wsf + OFF_WS_FLOATS + PWT_FLOATS + OBT_FLOATS;  // 512 B

    hipMemsetAsync(bias2, 0, GNUM * 64 * sizeof(float), stream);
    pw_prep<<<dim3(9, GNUM), dim3(256), 0, stream>>>(pw_w, dw_b, pwt, bias2);
    ow_prep<<<dim3(18, GNUM), dim3(256), 0, stream>>>(off_w, obt);
    offset_mfma<<<dim3(64, BATCH, GNUM), dim3(256), 0, stream>>>(
        x, obt, off_b, off_ws);
    deform_kernel<<<dim3(256, BATCH, GNUM), dim3(256), 0, stream>>>(
        x, off_ws, dw_w, pwt, bias2, pw_b, (float*)d_out);
}

// Round 7
// 215.528 us; speedup vs baseline: 4.6575x; 1.1845x over previous
//
#include <hip/hip_runtime.h>
#include <hip/hip_bf16.h>

#define HW 128
#define GNUM 2
#define BATCH 4
#define BHW2 (BATCH * HW * HW)                 // 65536
#define OFF_WS_FLOATS (GNUM * 18 * BHW2)       // planar [g*18+o][b][pix]
#define OBT_STRIDE (GNUM * 18 * 2 * 512)       // shorts per hi/lo sub-buffer
#define PWT_FLOATS 36864                       // 73728 shorts
#define OBT_FLOATS 36864                       // 73728 shorts (hi+lo)

typedef short s16x8 __attribute__((ext_vector_type(8)));
typedef float f32x4 __attribute__((ext_vector_type(4)));

__device__ inline unsigned short f2bf(float f) {
    union { float f; unsigned u; } v;
    v.f = f;
    unsigned r = (v.u + 0x7fffu + ((v.u >> 16) & 1u)) >> 16;
    return (unsigned short)r;
}
__device__ inline unsigned pk2bf(float lo, float hi) {   // v_cvt_pk_bf16_f32
    __hip_bfloat162 r = __float22bfloat162_rn(float2{lo, hi});
    return *(unsigned*)&r;
}
__device__ inline float blo(unsigned u) {
    union { unsigned u; float f; } v; v.u = u << 16; return v.f;
}
__device__ inline float bhi(unsigned u) {
    union { unsigned u; float f; } v; v.u = u & 0xffff0000u; return v.f;
}

// ---------------------------------------------------------------------------
// prep_kernel: bx 0..8 -> pw_prep(j=bx) ; bx 9..26 -> ow_prep(s=bx-9).
// pw: pw_w -> bf16 B-frags (validated R2-R6) + bias partial via atomicAdd.
// ow: off_w -> bf16 hi/lo B-frags (validated R5-R6).
// ---------------------------------------------------------------------------
__global__ __launch_bounds__(256) void prep_kernel(
    const float* __restrict__ pw_w, const float* __restrict__ dw_b,
    const float* __restrict__ off_w, unsigned short* __restrict__ pwt,
    unsigned short* __restrict__ obt, float* __restrict__ bias2) {
    const int g = blockIdx.y;
    const int t = threadIdx.x;
    if (blockIdx.x < 9) {
        const int j = blockIdx.x;
        const int wv = t >> 6, lane = t & 63;
        const int f = wv * 16 + (lane & 15);
        const int kbase = (lane >> 4) << 3;
        float part = 0.f;
#pragma unroll
        for (int ks = 0; ks < 2; ++ks)
#pragma unroll
            for (int i = 0; i < 8; ++i) {
                int kin = j * 64 + ks * 32 + kbase + i;
                float v = pw_w[(g * 576 + kin) * 64 + f];
                pwt[((((g * 9 + j) * 4 + wv) * 2 + ks) << 9) + lane * 8 + i] =
                    f2bf(v);
                part += v * dw_b[g * 576 + kin];
            }
        atomicAdd(&bias2[g * 64 + f], part);
    } else {
        const int s = blockIdx.x - 9;
        const int tap = s >> 1;
        for (int e = t; e < 1024; e += 256) {
            int nt = e >> 9, le = e & 511;
            int lane = le >> 3, i = le & 7;
            int k = ((lane >> 4) << 3) + i;
            int c = ((s & 1) << 5) + k;
            int n = (nt << 4) + (lane & 15);
            float v = (n < 18) ? off_w[((g * 9 + tap) * 64 + c) * 18 + n] : 0.f;
            unsigned short hi = f2bf(v);
            unsigned short lo = f2bf(v - blo(hi));
            int idx = (((g * 18 + s) * 2 + nt) << 9) + le;
            obt[idx] = hi;
            obt[OBT_STRIDE + idx] = lo;
        }
    }
}

// ---------------------------------------------------------------------------
// offset_mfma: 3x3 SAME conv 64->18 via bf16 MFMA, split-precision
// (AhBh + AlBh + AhBl).  8x8 px tiles -> 2048 blocks, 8 blocks/CU.
// grid (8 combos, 256 tiles): XCD k <- combo k (round-robin heuristic),
// so each XCD's L2 holds one (b,g) x-slice (4.2 MB).
// LDS: halo 10x10 x (32ch hi + 32ch lo), stride 72 sh = 14.4 KB.
// Wave wv owns m-tile (16 px); acc = 2 n-tiles (18 of 32 cols used).
// ---------------------------------------------------------------------------
__global__ __launch_bounds__(256) void offset_mfma(
    const float* __restrict__ x, const unsigned short* __restrict__ obt,
    const float* __restrict__ off_b, float* __restrict__ off_ws) {
    __shared__ unsigned short xh[100 * 72];
    const int b = blockIdx.x >> 1, g = blockIdx.x & 1;
    const int tileIdx = blockIdx.y;
    const int h0 = (tileIdx >> 4) << 3, w0 = (tileIdx & 15) << 3;
    const int t = threadIdx.x;
    const int lane = t & 63;
    const int wv = __builtin_amdgcn_readfirstlane(t >> 6);
    const int m = (wv << 4) + (lane & 15);       // pixel 0..63
    const int pyy = m >> 3, pxx = m & 7;
    const int kq = (lane >> 4) << 3;

    f32x4 acc[2];
    {
        const int col = lane & 15;
        float b0 = (col < 18) ? off_b[g * 18 + col] : 0.f;
        float b1 = (col + 16 < 18) ? off_b[g * 18 + col + 16] : 0.f;
        acc[0] = (f32x4){b0, b0, b0, b0};
        acc[1] = (f32x4){b1, b1, b1, b1};
    }
    for (int q = 0; q < 2; ++q) {
        if (q) __syncthreads();
        // stage halo 10x10 x 32ch (this q-half), fp32 -> hi/lo bf16
        for (int idx = t; idx < 800; idx += 256) {
            int sp = idx >> 3, cq = idx & 7;
            int sy = sp / 10, sx = sp - sy * 10;
            int gy = h0 - 1 + sy, gx = w0 - 1 + sx;
            uint2 hp = {0, 0}, lp = {0, 0};
            if ((unsigned)gy < HW && (unsigned)gx < HW) {
                const float4 v = *(const float4*)&x[(((b * HW + gy) * HW + gx)
                                                    << 7) +
                                                   (g << 6) + (q << 5) + (cq << 2)];
                hp.x = pk2bf(v.x, v.y);
                hp.y = pk2bf(v.z, v.w);
                lp.x = pk2bf(v.x - blo(hp.x), v.y - bhi(hp.x));
                lp.y = pk2bf(v.z - blo(hp.y), v.w - bhi(hp.y));
            }
            *(uint2*)&xh[sp * 72 + (cq << 2)] = hp;
            *(uint2*)&xh[sp * 72 + 32 + (cq << 2)] = lp;
        }
        __syncthreads();
        for (int tap = 0; tap < 9; ++tap) {
            const int s = (tap << 1) + q;
            const int ky = tap / 3, kx = tap - ky * 3;
            const int bidx = ((g * 18 + s) << 1) << 9;
            s16x8 bh0 = *(const s16x8*)&obt[bidx + lane * 8];
            s16x8 bh1 = *(const s16x8*)&obt[bidx + 512 + lane * 8];
            s16x8 bl0 = *(const s16x8*)&obt[OBT_STRIDE + bidx + lane * 8];
            s16x8 bl1 = *(const s16x8*)&obt[OBT_STRIDE + bidx + 512 + lane * 8];
            const int base = ((pyy + ky) * 10 + pxx + kx) * 72;
            s16x8 ah = *(const s16x8*)&xh[base + kq];
            s16x8 al = *(const s16x8*)&xh[base + 32 + kq];
            acc[0] = __builtin_amdgcn_mfma_f32_16x16x32_bf16(ah, bh0, acc[0],
                                                             0, 0, 0);
            acc[1] = __builtin_amdgcn_mfma_f32_16x16x32_bf16(ah, bh1, acc[1],
                                                             0, 0, 0);
            acc[0] = __builtin_amdgcn_mfma_f32_16x16x32_bf16(al, bh0, acc[0],
                                                             0, 0, 0);
            acc[1] = __builtin_amdgcn_mfma_f32_16x16x32_bf16(al, bh1, acc[1],
                                                             0, 0, 0);
            acc[0] = __builtin_amdgcn_mfma_f32_16x16x32_bf16(ah, bl0, acc[0],
                                                             0, 0, 0);
            acc[1] = __builtin_amdgcn_mfma_f32_16x16x32_bf16(ah, bl1, acc[1],
                                                             0, 0, 0);
        }
    }
    // epilogue: C row=(lane>>4)*4+i -> m' = wv*16+row; i-quad = 4 consecutive
    // x-pixels -> f32x4 store per n-tile.
    const int col = lane & 15;
    const int rq = (lane >> 4) << 2;
    const int m0 = (wv << 4) + rq;
    const int pixrow = b * (HW * HW) + (h0 + (m0 >> 3)) * HW + w0 + (m0 & 7);
#pragma unroll
    for (int nt = 0; nt < 2; ++nt) {
        int o = (nt << 4) + col;
        if (o < 18)
            *(f32x4*)&off_ws[(g * 18 + o) * BHW2 + pixrow] = acc[nt];
    }
}

// ---------------------------------------------------------------------------
// deform_kernel: W -> S (float4 gather, 16 lanes/sample) -> A (depthwise) ->
// B (pointwise MFMA).  grid (8 combos, 256 tiles) for XCD L2 locality.
// ---------------------------------------------------------------------------
__global__ __launch_bounds__(256, 6) void deform_kernel(
    const float* __restrict__ x, const float* __restrict__ off_ws,
    const float* __restrict__ dw_w, const unsigned short* __restrict__ pwt,
    const float* __restrict__ bias2, const float* __restrict__ pw_b,
    float* __restrict__ out) {
    __shared__ unsigned short samp[100 * 72];
    __shared__ unsigned short dwa[64 * 72];
    __shared__ float4 wlw[100];
    __shared__ int4 wli[100];
    const int b = blockIdx.x >> 1, g = blockIdx.x & 1;
    const int tileIdx = blockIdx.y;
    const int h0 = (tileIdx >> 4) << 3, w0 = (tileIdx & 15) << 3;
    const int t = threadIdx.x;
    const int lane = t & 63;
    const int wv = __builtin_amdgcn_readfirstlane(t >> 6);
    const int fb = wv << 4;
    const int p = lane;
    const int ayp = p >> 3, axp = p & 7;
    const int grp = t >> 4, sl = t & 15;   // 16-lane gather groups

    const float bs = bias2[g * 64 + fb + (lane & 15)] +
                     pw_b[g * 64 + fb + (lane & 15)];
    f32x4 acc[4];
#pragma unroll
    for (int mt = 0; mt < 4; ++mt) acc[mt] = (f32x4){bs, bs, bs, bs};

    for (int j = 0; j < 9; ++j) {
        const int jy = j / 3, jx = j - jy * 3;
        s16x8 bfr[2];
#pragma unroll
        for (int ks = 0; ks < 2; ++ks)
            bfr[ks] = *(const s16x8*)&pwt[((((g * 9 + j) * 4 + wv) * 2 + ks)
                                           << 9) + lane * 8];
        // ---- Phase W: bilinear weights + corner offsets, one thread per sp
        if (t < 100) {
            const int sp = t;
            const int spy = sp / 10, spx = sp - spy * 10;
            const int gy = h0 - 1 + spy, gx = w0 - 1 + spx;
            float4 w4 = {0.f, 0.f, 0.f, 0.f};
            int4 ii = {b << 21, 0, 0, 0};
            if ((unsigned)gy < HW && (unsigned)gx < HW) {
                const int pix = b * (HW * HW) + gy * HW + gx;
                const float ox = off_ws[(g * 18 + 2 * j) * BHW2 + pix];
                const float oy = off_ws[(g * 18 + 2 * j + 1) * BHW2 + pix];
                float xf = fminf(fmaxf((float)(gx + jx - 1) + ox, 0.f), 127.f);
                float yf = fminf(fmaxf((float)(gy + jy - 1) + oy, 0.f), 127.f);
                float x0 = floorf(xf), y0 = floorf(yf);
                float x1 = fminf(x0 + 1.f, 127.f);
                float y1 = fminf(y0 + 1.f, 127.f);
                w4.x = (x1 - xf) * (y1 - yf);   // (y0,x0)
                w4.y = (x1 - xf) * (yf - y0);   // (y1,x0)
                w4.z = (xf - x0) * (y1 - yf);   // (y0,x1)
                w4.w = (xf - x0) * (yf - y0);   // (y1,x1)
                const int x0i = (int)x0, y0i = (int)y0;
                ii.x = ((b * HW + y0i) * HW + x0i) << 7;
                ii.y = ((int)x1 - x0i) << 7;    // dx in elements
                ii.z = ((int)y1 - y0i) << 14;   // dy in elements
            }
            wlw[sp] = w4;
            wli[sp] = ii;
        }
        __syncthreads();
        // ---- Phase S: float4 gather; 16 sample positions per iteration,
        // 16 lanes per position (4 channels each).
        for (int it = 0; it < 7; ++it) {
            const int sp = (it << 4) + grp;
            if (sp < 100) {
                const float4 w4 = wlw[sp];
                const int4 ii = wli[sp];
                const float* xa = x + ii.x + (g << 6) + (sl << 2);
                const float4 va = *(const float4*)xa;
                const float4 vb = *(const float4*)(xa + ii.z);
                const float4 vc = *(const float4*)(xa + ii.y);
                const float4 vd = *(const float4*)(xa + ii.y + ii.z);
                float r0 = w4.x * va.x + w4.y * vb.x + w4.z * vc.x + w4.w * vd.x;
                float r1 = w4.x * va.y + w4.y * vb.y + w4.z * vc.y + w4.w * vd.y;
                float r2 = w4.x * va.z + w4.y * vb.z + w4.z * vc.z + w4.w * vd.z;
                float r3 = w4.x * va.w + w4.y * vb.w + w4.z * vc.w + w4.w * vd.w;
                uint2 pk;
                pk.x = pk2bf(r0, r1);
                pk.y = pk2bf(r2, r3);
                *(uint2*)&samp[sp * 72 + (sl << 2)] = pk;
            }
        }
        __syncthreads();
        // ---- Phase A: depthwise 3x3, channels [fb, fb+16), bf16 in/out
#pragma unroll
        for (int cq = 0; cq < 2; ++cq) {
            const int c8 = fb + (cq << 3);
            float d0 = 0.f, d1 = 0.f, d2 = 0.f, d3 = 0.f;
            float d4 = 0.f, d5 = 0.f, d6 = 0.f, d7 = 0.f;
#pragma unroll
            for (int ky = 0; ky < 3; ++ky)
#pragma unroll
                for (int kx = 0; kx < 3; ++kx) {
                    const uint4 hv = *(const uint4*)&samp
                        [((ayp + ky) * 10 + axp + kx) * 72 + c8];
                    const float* wr =
                        &dw_w[((g * 3 + ky) * 3 + kx) * 576 + (j << 6) + c8];
                    d0 += blo(hv.x) * wr[0]; d1 += bhi(hv.x) * wr[1];
                    d2 += blo(hv.y) * wr[2]; d3 += bhi(hv.y) * wr[3];
                    d4 += blo(hv.z) * wr[4]; d5 += bhi(hv.z) * wr[5];
                    d6 += blo(hv.w) * wr[6]; d7 += bhi(hv.w) * wr[7];
                }
            uint4 pk;
            pk.x = pk2bf(d0, d1);
            pk.y = pk2bf(d2, d3);
            pk.z = pk2bf(d4, d5);
            pk.w = pk2bf(d6, d7);
            *(uint4*)&dwa[p * 72 + c8] = pk;
        }
        __syncthreads();
        // ---- Phase B: pointwise via MFMA
#pragma unroll
        for (int ks = 0; ks < 2; ++ks)
#pragma unroll
            for (int mt = 0; mt < 4; ++mt) {
                s16x8 af = *(const s16x8*)&dwa[(mt * 16 + (lane & 15)) * 72 +
                                               ks * 32 + ((lane >> 4) << 3)];
                acc[mt] = __builtin_amdgcn_mfma_f32_16x16x32_bf16(
                    af, bfr[ks], acc[mt], 0, 0, 0);
            }
    }
    // ---- epilogue: C-layout col=lane&15, row=(lane>>4)*4+i
    const int col = lane & 15;
    const int rq = (lane >> 4) << 2;
#pragma unroll
    for (int mt = 0; mt < 4; ++mt)
#pragma unroll
        for (int i = 0; i < 4; ++i) {
            int m = mt * 16 + rq + i;
            out[((b * HW + h0 + (m >> 3)) * HW + (w0 + (m & 7))) * 128 +
                (g << 6) + fb + col] = acc[mt][i];
        }
}

extern "C" void kernel_launch(void* const* d_in, const int* in_sizes, int n_in,
                              void* d_out, int out_size, void* d_ws,
                              size_t ws_size, hipStream_t stream) {
    const float* x = (const float*)d_in[0];
    const float* off_w = (const float*)d_in[1];
    const float* off_b = (const float*)d_in[2];
    const float* dw_w = (const float*)d_in[3];
    const float* dw_b = (const float*)d_in[4];
    const float* pw_w = (const float*)d_in[5];
    const float* pw_b = (const float*)d_in[6];

    // workspace layout (floats): [off_ws | pwt | obt | bias2]
    float* wsf = (float*)d_ws;
    float* off_ws = wsf;                                        // 9.44 MB
    unsigned short* pwt =
        (unsigned short*)(wsf + OFF_WS_FLOATS);                 // 147456 B
    unsigned short* obt =
        (unsigned short*)(wsf + OFF_WS_FLOATS + PWT_FLOATS);    // 147456 B
    float* bias2 = wsf + OFF_WS_FLOATS + PWT_FLOATS + OBT_FLOATS;  // 512 B

    hipMemsetAsync(bias2, 0, GNUM * 64 * sizeof(float), stream);
    prep_kernel<<<dim3(27, GNUM), dim3(256), 0, stream>>>(pw_w, dw_b, off_w,
                                                          pwt, obt, bias2);
    offset_mfma<<<dim3(BATCH * GNUM, 256), dim3(256), 0, stream>>>(
        x, obt, off_b, off_ws);
    deform_kernel<<<dim3(BATCH * GNUM, 256), dim3(256), 0, stream>>>(
        x, off_ws, dw_w, pwt, bias2, pw_b, (float*)d_out);
}

// Round 8
// 207.102 us; speedup vs baseline: 4.8470x; 1.0407x over previous
//
#include <hip/hip_runtime.h>
#include <hip/hip_bf16.h>

#define HW 128
#define GNUM 2
#define BATCH 4
#define OBT_STRIDE (GNUM * 18 * 2 * 512)       // shorts per hi/lo sub-buffer
#define PWT_FLOATS 36864                       // 73728 shorts
#define OBT_FLOATS 36864                       // 73728 shorts (hi+lo)

typedef short s16x8 __attribute__((ext_vector_type(8)));
typedef float f32x4 __attribute__((ext_vector_type(4)));

__device__ inline unsigned short f2bf(float f) {
    union { float f; unsigned u; } v;
    v.f = f;
    unsigned r = (v.u + 0x7fffu + ((v.u >> 16) & 1u)) >> 16;
    return (unsigned short)r;
}
__device__ inline unsigned pk2bf(float lo, float hi) {   // v_cvt_pk_bf16_f32
    __hip_bfloat162 r = __float22bfloat162_rn(float2{lo, hi});
    return *(unsigned*)&r;
}
__device__ inline float blo(unsigned u) {
    union { unsigned u; float f; } v; v.u = u << 16; return v.f;
}
__device__ inline float bhi(unsigned u) {
    union { unsigned u; float f; } v; v.u = u & 0xffff0000u; return v.f;
}

// ---------------------------------------------------------------------------
// prep_kernel: bx 0..8 -> pw_w -> bf16 B-frags + bias partial (validated);
// bx 9..26 -> off_w -> bf16 hi/lo B-frags (validated R5-R7).
// ---------------------------------------------------------------------------
__global__ __launch_bounds__(256) void prep_kernel(
    const float* __restrict__ pw_w, const float* __restrict__ dw_b,
    const float* __restrict__ off_w, unsigned short* __restrict__ pwt,
    unsigned short* __restrict__ obt, float* __restrict__ bias2) {
    const int g = blockIdx.y;
    const int t = threadIdx.x;
    if (blockIdx.x < 9) {
        const int j = blockIdx.x;
        const int wv = t >> 6, lane = t & 63;
        const int f = wv * 16 + (lane & 15);
        const int kbase = (lane >> 4) << 3;
        float part = 0.f;
#pragma unroll
        for (int ks = 0; ks < 2; ++ks)
#pragma unroll
            for (int i = 0; i < 8; ++i) {
                int kin = j * 64 + ks * 32 + kbase + i;
                float v = pw_w[(g * 576 + kin) * 64 + f];
                pwt[((((g * 9 + j) * 4 + wv) * 2 + ks) << 9) + lane * 8 + i] =
                    f2bf(v);
                part += v * dw_b[g * 576 + kin];
            }
        atomicAdd(&bias2[g * 64 + f], part);
    } else {
        const int s = blockIdx.x - 9;
        const int tap = s >> 1;
        for (int e = t; e < 1024; e += 256) {
            int nt = e >> 9, le = e & 511;
            int lane = le >> 3, i = le & 7;
            int k = ((lane >> 4) << 3) + i;
            int c = ((s & 1) << 5) + k;
            int n = (nt << 4) + (lane & 15);
            float v = (n < 18) ? off_w[((g * 9 + tap) * 64 + c) * 18 + n] : 0.f;
            unsigned short hi = f2bf(v);
            unsigned short lo = f2bf(v - blo(hi));
            int idx = (((g * 18 + s) * 2 + nt) << 9) + le;
            obt[idx] = hi;
            obt[OBT_STRIDE + idx] = lo;
        }
    }
}

// ---------------------------------------------------------------------------
// deform_fused: ONE kernel per 8x8 output tile of (b,g):
//   Stage 0: offset conv (3x3 SAME, 64->18, split-precision bf16 MFMA) for
//            the 10x10 halo positions, from a 12x12 x-halo -> offs[] in LDS.
//   Stage 1: per tap j: W (bilinear wts) -> S (float4 gather) ->
//            A (depthwise) -> B (pointwise MFMA).  (validated R5-R7 pattern)
// LDS union (34,016 B -> 4 blocks/CU):
//   [0,23616):  xh ushort[144*72] (20.7 KB)  ALIASED WITH
//               samp ushort[100*72] @0 + dwa ushort[64*72] @14400
//   [23616..):  offs float[100*18]  (7.2 KB)
//   [30816..):  wlw float4[100] ; wli int4[100]  (3.2 KB)
// ---------------------------------------------------------------------------
__global__ __launch_bounds__(256, 4) void deform_fused(
    const float* __restrict__ x, const unsigned short* __restrict__ obt,
    const float* __restrict__ off_b, const float* __restrict__ dw_w,
    const unsigned short* __restrict__ pwt, const float* __restrict__ bias2,
    const float* __restrict__ pw_b, float* __restrict__ out) {
    __shared__ char smem[34016];
    unsigned short* xh = (unsigned short*)smem;            // stage 0 only
    unsigned short* samp = (unsigned short*)smem;          // stage 1
    unsigned short* dwa = (unsigned short*)(smem + 14400); // stage 1
    float* offs = (float*)(smem + 23616);
    float4* wlw = (float4*)(smem + 30816);
    int4* wli = (int4*)(smem + 32416);

    const int b = blockIdx.x >> 1, g = blockIdx.x & 1;
    const int tileIdx = blockIdx.y;
    const int h0 = (tileIdx >> 4) << 3, w0 = (tileIdx & 15) << 3;
    const int t = threadIdx.x;
    const int lane = t & 63;
    const int wv = __builtin_amdgcn_readfirstlane(t >> 6);
    const int kq = (lane >> 4) << 3;
    const int col = lane & 15;
    const int rq = (lane >> 4) << 2;

    // ================= Stage 0: offset conv for the halo =================
    f32x4 oacc[2][2];
#pragma unroll
    for (int sl = 0; sl < 2; ++sl)
#pragma unroll
        for (int nt = 0; nt < 2; ++nt) oacc[sl][nt] = (f32x4){0.f, 0.f, 0.f, 0.f};
    int mbase[2];
#pragma unroll
    for (int sl = 0; sl < 2; ++sl) {
        int mt = wv + (sl << 2);
        int m = mt * 16 + col;
        if (mt < 7 && m < 100) {
            int opy = m / 10, opx = m - opy * 10;
            mbase[sl] = opy * 12 + opx;
        } else
            mbase[sl] = 0;
    }
    for (int q = 0; q < 2; ++q) {
        if (q) __syncthreads();
        // stage 12x12 halo x 32ch (this q-half), fp32 -> hi/lo bf16
        for (int idx = t; idx < 144 * 8; idx += 256) {
            int sp = idx >> 3, cq = idx & 7;
            int sy = sp / 12, sx = sp - sy * 12;
            int gy = h0 - 2 + sy, gx = w0 - 2 + sx;
            uint2 hp = {0, 0}, lp = {0, 0};
            if ((unsigned)gy < HW && (unsigned)gx < HW) {
                const float4 v = *(const float4*)&x[(((b * HW + gy) * HW + gx)
                                                    << 7) +
                                                   (g << 6) + (q << 5) + (cq << 2)];
                hp.x = pk2bf(v.x, v.y);
                hp.y = pk2bf(v.z, v.w);
                lp.x = pk2bf(v.x - blo(hp.x), v.y - bhi(hp.x));
                lp.y = pk2bf(v.z - blo(hp.y), v.w - bhi(hp.y));
            }
            *(uint2*)&xh[sp * 72 + (cq << 2)] = hp;
            *(uint2*)&xh[sp * 72 + 32 + (cq << 2)] = lp;
        }
        __syncthreads();
        for (int tap = 0; tap < 9; ++tap) {
            const int s = (tap << 1) + q;
            const int ky = tap / 3, kx = tap - ky * 3;
            const int shift = ky * 12 + kx;
            const int bidx = ((g * 18 + s) << 1) << 9;
            s16x8 bh0 = *(const s16x8*)&obt[bidx + lane * 8];
            s16x8 bh1 = *(const s16x8*)&obt[bidx + 512 + lane * 8];
            s16x8 bl0 = *(const s16x8*)&obt[OBT_STRIDE + bidx + lane * 8];
            s16x8 bl1 = *(const s16x8*)&obt[OBT_STRIDE + bidx + 512 + lane * 8];
#pragma unroll
            for (int sl = 0; sl < 2; ++sl) {
                if (wv + (sl << 2) < 7) {   // wave-uniform guard
                    const int base2 = (mbase[sl] + shift) * 72 + kq;
                    s16x8 ah = *(const s16x8*)&xh[base2];
                    s16x8 al = *(const s16x8*)&xh[base2 + 32];
                    oacc[sl][0] = __builtin_amdgcn_mfma_f32_16x16x32_bf16(
                        ah, bh0, oacc[sl][0], 0, 0, 0);
                    oacc[sl][1] = __builtin_amdgcn_mfma_f32_16x16x32_bf16(
                        ah, bh1, oacc[sl][1], 0, 0, 0);
                    oacc[sl][0] = __builtin_amdgcn_mfma_f32_16x16x32_bf16(
                        al, bh0, oacc[sl][0], 0, 0, 0);
                    oacc[sl][1] = __builtin_amdgcn_mfma_f32_16x16x32_bf16(
                        al, bh1, oacc[sl][1], 0, 0, 0);
                    oacc[sl][0] = __builtin_amdgcn_mfma_f32_16x16x32_bf16(
                        ah, bl0, oacc[sl][0], 0, 0, 0);
                    oacc[sl][1] = __builtin_amdgcn_mfma_f32_16x16x32_bf16(
                        ah, bl1, oacc[sl][1], 0, 0, 0);
                }
            }
        }
    }
    // write offs[m][o] = conv + off_b   (C-layout: row = rq+i, col)
#pragma unroll
    for (int sl = 0; sl < 2; ++sl) {
        int mt = wv + (sl << 2);
        if (mt < 7) {
#pragma unroll
            for (int nt = 0; nt < 2; ++nt) {
                int o = (nt << 4) + col;
                if (o < 18) {
                    float ob = off_b[g * 18 + o];
#pragma unroll
                    for (int i = 0; i < 4; ++i) {
                        int m = mt * 16 + rq + i;
                        if (m < 100) offs[m * 18 + o] = oacc[sl][nt][i] + ob;
                    }
                }
            }
        }
    }
    __syncthreads();   // offs visible; xh reads done before samp overwrites

    // ================= Stage 1: sample -> depthwise -> pointwise =========
    const int fb = wv << 4;
    const int p = lane;
    const int ayp = p >> 3, axp = p & 7;
    const int grp = t >> 4, sl16 = t & 15;

    const float bs = bias2[g * 64 + fb + col] + pw_b[g * 64 + fb + col];
    f32x4 acc[4];
#pragma unroll
    for (int mt = 0; mt < 4; ++mt) acc[mt] = (f32x4){bs, bs, bs, bs};

    for (int j = 0; j < 9; ++j) {
        const int jy = j / 3, jx = j - jy * 3;
        s16x8 bfr[2];
#pragma unroll
        for (int ks = 0; ks < 2; ++ks)
            bfr[ks] = *(const s16x8*)&pwt[((((g * 9 + j) * 4 + wv) * 2 + ks)
                                           << 9) + lane * 8];
        // ---- Phase W: bilinear weights + corner offsets, one thread per sp
        if (t < 100) {
            const int sp = t;
            const int spy = sp / 10, spx = sp - spy * 10;
            const int gy = h0 - 1 + spy, gx = w0 - 1 + spx;
            float4 w4 = {0.f, 0.f, 0.f, 0.f};
            int4 ii = {b << 21, 0, 0, 0};
            if ((unsigned)gy < HW && (unsigned)gx < HW) {
                const float ox = offs[sp * 18 + 2 * j];
                const float oy = offs[sp * 18 + 2 * j + 1];
                float xf = fminf(fmaxf((float)(gx + jx - 1) + ox, 0.f), 127.f);
                float yf = fminf(fmaxf((float)(gy + jy - 1) + oy, 0.f), 127.f);
                float x0 = floorf(xf), y0 = floorf(yf);
                float x1 = fminf(x0 + 1.f, 127.f);
                float y1 = fminf(y0 + 1.f, 127.f);
                w4.x = (x1 - xf) * (y1 - yf);
                w4.y = (x1 - xf) * (yf - y0);
                w4.z = (xf - x0) * (y1 - yf);
                w4.w = (xf - x0) * (yf - y0);
                const int x0i = (int)x0, y0i = (int)y0;
                ii.x = ((b * HW + y0i) * HW + x0i) << 7;
                ii.y = ((int)x1 - x0i) << 7;
                ii.z = ((int)y1 - y0i) << 14;
            }
            wlw[sp] = w4;
            wli[sp] = ii;
        }
        __syncthreads();
        // ---- Phase S: float4 gather; 16 lanes per sample position
        for (int it = 0; it < 7; ++it) {
            const int sp = (it << 4) + grp;
            if (sp < 100) {
                const float4 w4 = wlw[sp];
                const int4 ii = wli[sp];
                const float* xa = x + ii.x + (g << 6) + (sl16 << 2);
                const float4 va = *(const float4*)xa;
                const float4 vb = *(const float4*)(xa + ii.z);
                const float4 vc = *(const float4*)(xa + ii.y);
                const float4 vd = *(const float4*)(xa + ii.y + ii.z);
                float r0 = w4.x * va.x + w4.y * vb.x + w4.z * vc.x + w4.w * vd.x;
                float r1 = w4.x * va.y + w4.y * vb.y + w4.z * vc.y + w4.w * vd.y;
                float r2 = w4.x * va.z + w4.y * vb.z + w4.z * vc.z + w4.w * vd.z;
                float r3 = w4.x * va.w + w4.y * vb.w + w4.z * vc.w + w4.w * vd.w;
                uint2 pk;
                pk.x = pk2bf(r0, r1);
                pk.y = pk2bf(r2, r3);
                *(uint2*)&samp[sp * 72 + (sl16 << 2)] = pk;
            }
        }
        __syncthreads();
        // ---- Phase A: depthwise 3x3, channels [fb, fb+16)
#pragma unroll
        for (int cq = 0; cq < 2; ++cq) {
            const int c8 = fb + (cq << 3);
            float d0 = 0.f, d1 = 0.f, d2 = 0.f, d3 = 0.f;
            float d4 = 0.f, d5 = 0.f, d6 = 0.f, d7 = 0.f;
#pragma unroll
            for (int ky = 0; ky < 3; ++ky)
#pragma unroll
                for (int kx = 0; kx < 3; ++kx) {
                    const uint4 hv = *(const uint4*)&samp
                        [((ayp + ky) * 10 + axp + kx) * 72 + c8];
                    const float* wr =
                        &dw_w[((g * 3 + ky) * 3 + kx) * 576 + (j << 6) + c8];
                    d0 += blo(hv.x) * wr[0]; d1 += bhi(hv.x) * wr[1];
                    d2 += blo(hv.y) * wr[2]; d3 += bhi(hv.y) * wr[3];
                    d4 += blo(hv.z) * wr[4]; d5 += bhi(hv.z) * wr[5];
                    d6 += blo(hv.w) * wr[6]; d7 += bhi(hv.w) * wr[7];
                }
            uint4 pk;
            pk.x = pk2bf(d0, d1);
            pk.y = pk2bf(d2, d3);
            pk.z = pk2bf(d4, d5);
            pk.w = pk2bf(d6, d7);
            *(uint4*)&dwa[p * 72 + c8] = pk;
        }
        __syncthreads();
        // ---- Phase B: pointwise via MFMA
#pragma unroll
        for (int ks = 0; ks < 2; ++ks)
#pragma unroll
            for (int mt = 0; mt < 4; ++mt) {
                s16x8 af = *(const s16x8*)&dwa[(mt * 16 + col) * 72 + ks * 32 +
                                               kq];
                acc[mt] = __builtin_amdgcn_mfma_f32_16x16x32_bf16(
                    af, bfr[ks], acc[mt], 0, 0, 0);
            }
    }
    // ---- epilogue: C-layout col=lane&15, row=(lane>>4)*4+i
#pragma unroll
    for (int mt = 0; mt < 4; ++mt)
#pragma unroll
        for (int i = 0; i < 4; ++i) {
            int m = mt * 16 + rq + i;
            out[((b * HW + h0 + (m >> 3)) * HW + (w0 + (m & 7))) * 128 +
                (g << 6) + fb + col] = acc[mt][i];
        }
}

extern "C" void kernel_launch(void* const* d_in, const int* in_sizes, int n_in,
                              void* d_out, int out_size, void* d_ws,
                              size_t ws_size, hipStream_t stream) {
    const float* x = (const float*)d_in[0];
    const float* off_w = (const float*)d_in[1];
    const float* off_b = (const float*)d_in[2];
    const float* dw_w = (const float*)d_in[3];
    const float* dw_b = (const float*)d_in[4];
    const float* pw_w = (const float*)d_in[5];
    const float* pw_b = (const float*)d_in[6];

    // workspace layout (floats): [pwt | obt | bias2]
    float* wsf = (float*)d_ws;
    unsigned short* pwt = (unsigned short*)wsf;                // 147456 B
    unsigned short* obt = (unsigned short*)(wsf + PWT_FLOATS); // 147456 B
    float* bias2 = wsf + PWT_FLOATS + OBT_FLOATS;              // 512 B

    hipMemsetAsync(bias2, 0, GNUM * 64 * sizeof(float), stream);
    prep_kernel<<<dim3(27, GNUM), dim3(256), 0, stream>>>(pw_w, dw_b, off_w,
                                                          pwt, obt, bias2);
    deform_fused<<<dim3(BATCH * GNUM, 256), dim3(256), 0, stream>>>(
        x, obt, off_b, dw_w, pwt, bias2, pw_b, (float*)d_out);
}